// Round 1
// 72.360 us; speedup vs baseline: 1.0308x; 1.0308x over previous
//
#include <hip/hip_runtime.h>

// Problem constants (from reference): B=8, M=64, N=64, P=3, Q=3, GRID=512, DIM=3
#define GRID_PTS 512
#define M_CTRL   64
#define N_CTRL   64

// One block per (b, g) row.
// Stage 1: lanes 0..63 compute Su[n] (u-direction contraction) into LDS.
// Stage 2: thread t handles h = j*128+t (j=0..3) -> vspan/Nv loads are
//          perfectly lane-contiguous; results staged to LDS (stride-3 word
//          writes: gcd(3,32)=1 -> conflict-free).
// Stage 3: row written back as 384 lane-contiguous float4 stores (1024 B
//          per wave-instruction, ideal line packing) instead of the old
//          48-B-stride dwordx4 pattern (3x line-touch inflation).
__global__ __launch_bounds__(128) void surfeval_kernel(
    const float4* __restrict__ ctrl,   // (B, M, N) of float4 (xyz*w, w)
    const int*    __restrict__ uspan,  // (GRID)
    const int*    __restrict__ vspan,  // (GRID)
    const float4* __restrict__ Nu,     // (GRID) basis coeffs, 4 per g
    const float4* __restrict__ Nv,     // (GRID)
    float*        __restrict__ out)    // (B, GRID, GRID, 3)
{
    __shared__ float4 Su[N_CTRL];
    __shared__ float  obuf[GRID_PTS * 3];   // 6 KiB output staging

    const int blk = blockIdx.x;            // b*GRID + g
    const int g   = blk & (GRID_PTS - 1);
    const int b   = blk >> 9;
    const int t   = threadIdx.x;

    // ---- Stage 1: Su[n] = sum_r Nu[g][r] * ctrl[b][uspan[g]-3+r][n] ----
    if (t < N_CTRL) {
        const int    iu = uspan[g] - 3;
        const float4 nu = Nu[g];
        const float4* cp = ctrl + ((size_t)b * M_CTRL + iu) * N_CTRL + t;
        const float4 c0 = cp[0 * N_CTRL];
        const float4 c1 = cp[1 * N_CTRL];
        const float4 c2 = cp[2 * N_CTRL];
        const float4 c3 = cp[3 * N_CTRL];
        float4 s;
        s.x = nu.x * c0.x + nu.y * c1.x + nu.z * c2.x + nu.w * c3.x;
        s.y = nu.x * c0.y + nu.y * c1.y + nu.z * c2.y + nu.w * c3.y;
        s.z = nu.x * c0.z + nu.y * c1.z + nu.z * c2.z + nu.w * c3.z;
        s.w = nu.x * c0.w + nu.y * c1.w + nu.z * c2.w + nu.w * c3.w;
        Su[t] = s;
    }
    __syncthreads();

    // ---- Stage 2: v-direction contraction, h = j*128 + t ----
#pragma unroll
    for (int j = 0; j < 4; ++j) {
        const int    h  = j * 128 + t;
        const int    iv = vspan[h] - 3;          // lane-contiguous dword load
        const float4 nv = Nv[h];                 // lane-contiguous 16B load
        const float4 a0 = Su[iv + 0];
        const float4 a1 = Su[iv + 1];
        const float4 a2 = Su[iv + 2];
        const float4 a3 = Su[iv + 3];
        const float sx = nv.x * a0.x + nv.y * a1.x + nv.z * a2.x + nv.w * a3.x;
        const float sy = nv.x * a0.y + nv.y * a1.y + nv.z * a2.y + nv.w * a3.y;
        const float sz = nv.x * a0.z + nv.y * a1.z + nv.z * a2.z + nv.w * a3.z;
        const float sw = nv.x * a0.w + nv.y * a1.w + nv.z * a2.w + nv.w * a3.w;
        const float inv = __builtin_amdgcn_rcpf(sw);  // |tol|=7.8e-3 >> rcp err
        obuf[h * 3 + 0] = sx * inv;   // stride-3 words across lanes:
        obuf[h * 3 + 1] = sy * inv;   // gcd(3,32)=1 -> 2 lanes/bank (free)
        obuf[h * 3 + 2] = sz * inv;
    }
    __syncthreads();

    // ---- Stage 3: fully-coalesced row writeback (384 float4) ----
    const float4* ob4 = (const float4*)obuf;
    float4* op = (float4*)(out + (size_t)blk * (GRID_PTS * 3));
    op[t      ] = ob4[t      ];
    op[t + 128] = ob4[t + 128];
    op[t + 256] = ob4[t + 256];
}

extern "C" void kernel_launch(void* const* d_in, const int* in_sizes, int n_in,
                              void* d_out, int out_size, void* d_ws, size_t ws_size,
                              hipStream_t stream) {
    const float4* ctrl  = (const float4*)d_in[0];  // (8, 64, 64, 4) f32
    const int*    uspan = (const int*)d_in[1];     // (512)
    const int*    vspan = (const int*)d_in[2];     // (512)
    const float4* Nu    = (const float4*)d_in[3];  // (512, 4) f32
    const float4* Nv    = (const float4*)d_in[4];  // (512, 4) f32
    float*        out   = (float*)d_out;           // (8, 512, 512, 3) f32

    const int blocks = 8 * GRID_PTS;  // one per (b, g)
    surfeval_kernel<<<blocks, 128, 0, stream>>>(ctrl, uspan, vspan, Nu, Nv, out);
}

// Round 2
// 71.175 us; speedup vs baseline: 1.0479x; 1.0167x over previous
//
#include <hip/hip_runtime.h>

// Problem constants (from reference): B=8, M=64, N=64, P=3, Q=3, GRID=512, DIM=3
#define GRID_PTS 512
#define M_CTRL   64
#define N_CTRL   64
#define ROWS     4     // consecutive g-rows per block

// One block per (b, 4-row g-tile); 512 threads, 1024 blocks total.
//  Prefetch: every thread loads its own vspan[t]/Nv[t] ONCE (vs 4096x
//            redundant per-block loads before) and before stage 1, so the
//            latency hides under the u-contraction.
//  Stage 1:  waves 0..3 each build one Su row (g = gbase+wave) in LDS;
//            uspan/Nu are wave-uniform -> scalar loads.
//  Stage 2:  thread t evaluates h=t against all 4 Su rows; pure LDS+VALU
//            (no global loads after the barrier). obuf word index 3t+c:
//            stride-3 across lanes -> 2 lanes/bank = conflict-free.
//  Stage 3:  4 consecutive g-rows are contiguous in out, so writeback is a
//            flat 24 KiB copy: 3 rounds of 512 lane-contiguous float4.
__global__ __launch_bounds__(512) void surfeval_kernel(
    const float4* __restrict__ ctrl,   // (B, M, N) of float4 (xyz*w, w)
    const int*    __restrict__ uspan,  // (GRID)
    const int*    __restrict__ vspan,  // (GRID)
    const float4* __restrict__ Nu,     // (GRID)
    const float4* __restrict__ Nv,     // (GRID)
    float*        __restrict__ out)    // (B, GRID, GRID, 3)
{
    __shared__ float4 Su[ROWS][N_CTRL];          // 4 KiB
    __shared__ float  obuf[ROWS * GRID_PTS * 3]; // 24 KiB

    const int blk   = blockIdx.x;        // b*128 + gtile
    const int b     = blk >> 7;
    const int gbase = (blk & 127) << 2;
    const int t     = threadIdx.x;

    // ---- Prefetch v-direction data (independent of stage 1) ----
    const int    iv = vspan[t] - 3;      // lane-contiguous dword load
    const float4 nv = Nv[t];             // lane-contiguous 16B load

    // ---- Stage 1: Su[row][n] = sum_r Nu[g][r] * ctrl[b][iu+r][n] ----
    if (t < ROWS * N_CTRL) {
        const int row = t >> 6;          // wave-uniform (wave id 0..3)
        const int n   = t & 63;
        const int g   = gbase + row;
        const int iu  = uspan[g] - 3;    // wave-uniform -> s_load
        const float4 nu = Nu[g];
        const float4* cp = ctrl + ((size_t)b * M_CTRL + iu) * N_CTRL + n;
        const float4 c0 = cp[0 * N_CTRL];
        const float4 c1 = cp[1 * N_CTRL];
        const float4 c2 = cp[2 * N_CTRL];
        const float4 c3 = cp[3 * N_CTRL];
        float4 s;
        s.x = nu.x * c0.x + nu.y * c1.x + nu.z * c2.x + nu.w * c3.x;
        s.y = nu.x * c0.y + nu.y * c1.y + nu.z * c2.y + nu.w * c3.y;
        s.z = nu.x * c0.z + nu.y * c1.z + nu.z * c2.z + nu.w * c3.z;
        s.w = nu.x * c0.w + nu.y * c1.w + nu.z * c2.w + nu.w * c3.w;
        Su[row][n] = s;
    }
    __syncthreads();

    // ---- Stage 2: h = t against all 4 rows (pure LDS + VALU) ----
#pragma unroll
    for (int r = 0; r < ROWS; ++r) {
        const float4 a0 = Su[r][iv + 0];
        const float4 a1 = Su[r][iv + 1];
        const float4 a2 = Su[r][iv + 2];
        const float4 a3 = Su[r][iv + 3];
        const float sx = nv.x * a0.x + nv.y * a1.x + nv.z * a2.x + nv.w * a3.x;
        const float sy = nv.x * a0.y + nv.y * a1.y + nv.z * a2.y + nv.w * a3.y;
        const float sz = nv.x * a0.z + nv.y * a1.z + nv.z * a2.z + nv.w * a3.z;
        const float sw = nv.x * a0.w + nv.y * a1.w + nv.z * a2.w + nv.w * a3.w;
        const float inv = __builtin_amdgcn_rcpf(sw);  // |tol|=7.8e-3 >> rcp err
        float* ob = obuf + r * (GRID_PTS * 3) + t * 3;
        ob[0] = sx * inv;
        ob[1] = sy * inv;
        ob[2] = sz * inv;
    }
    __syncthreads();

    // ---- Stage 3: flat 24 KiB coalesced writeback ----
    const float4* ob4 = (const float4*)obuf;
    float4* op = (float4*)(out + (size_t)(b * GRID_PTS + gbase) * (GRID_PTS * 3));
#pragma unroll
    for (int k = 0; k < 3; ++k)
        op[t + k * 512] = ob4[t + k * 512];
}

extern "C" void kernel_launch(void* const* d_in, const int* in_sizes, int n_in,
                              void* d_out, int out_size, void* d_ws, size_t ws_size,
                              hipStream_t stream) {
    const float4* ctrl  = (const float4*)d_in[0];  // (8, 64, 64, 4) f32
    const int*    uspan = (const int*)d_in[1];     // (512)
    const int*    vspan = (const int*)d_in[2];     // (512)
    const float4* Nu    = (const float4*)d_in[3];  // (512, 4) f32
    const float4* Nv    = (const float4*)d_in[4];  // (512, 4) f32
    float*        out   = (float*)d_out;           // (8, 512, 512, 3) f32

    const int blocks = 8 * (GRID_PTS / ROWS);      // 1024: one per (b, g-tile)
    surfeval_kernel<<<blocks, 512, 0, stream>>>(ctrl, uspan, vspan, Nu, Nv, out);
}